// Round 1
// baseline (10109.237 us; speedup 1.0000x reference)
//
#include <hip/hip_runtime.h>

// Problem constants (fixed by reference setup)
#define B_ 32
#define T_ 8192
#define I_ 16
#define H_ 128
#define G_ 512   // 4*H
#define P_ 1024
#define O_ 3

__device__ __forceinline__ float sigmoid_f(float x) {
    return 1.f / (1.f + __expf(-x));
}
__device__ __forceinline__ float tanh_f(float x) {
    // 2*sigmoid(2x)-1 ; saturates correctly for large |x| (inf handled: 2/inf-1 = -1)
    return 2.f / (1.f + __expf(-2.f * x)) - 1.f;
}

// One block per batch element. 512 threads = one per gate row.
// Thread g owns row g of W_ih/W_hh/biases (PyTorch gate order i,f,g,o).
// Threads 0..127 additionally own the c_j / h_j state update.
// Threads 0..383 (= o*128+j) additionally own the fused FC reduction.
__global__ __launch_bounds__(512, 2) void lstm_fused(
    const float* __restrict__ x,      // [B,T,16]
    const float* __restrict__ W_ih,   // [512,16]
    const float* __restrict__ W_hh,   // [512,128]
    const float* __restrict__ b_ih,   // [512]
    const float* __restrict__ b_hh,   // [512]
    const float* __restrict__ W_fc,   // [3,128]
    float* __restrict__ sums,         // [B,P,3]  (pre-zeroed)
    float* __restrict__ counts)       // [B,P]    (pre-zeroed)
{
    const int b   = blockIdx.x;
    const int tid = threadIdx.x;

    __shared__ float h_s[H_];        // hidden state (float4-aligned)
    __shared__ float x_s[I_];        // current timestep input
    __shared__ float g_s[G_];        // activated gates

    // ---- load weights into registers (one-time) ----
    float4 whh[H_ / 4];
    {
        const float4* wrow = (const float4*)(W_hh + tid * H_);
        #pragma unroll
        for (int k = 0; k < H_ / 4; ++k) whh[k] = wrow[k];
    }
    float wih[I_];
    #pragma unroll
    for (int k = 0; k < I_; ++k) wih[k] = W_ih[tid * I_ + k];
    const float bias = b_ih[tid] + b_hh[tid];

    float wfc = 0.f;
    if (tid < O_ * H_) wfc = W_fc[tid];   // tid = o*128+j maps directly onto row-major [3,128]

    // ---- init state ----
    float c = 0.f;
    if (tid < H_) h_s[tid] = 0.f;
    if (tid < I_) x_s[tid] = x[(b * T_ + 0) * I_ + tid];
    __syncthreads();

    int id_prev = -1;   // photo id of previous timestep (-1 = invalid)
    float xnext = 0.f;

    for (int t = 0; t < T_; ++t) {
        // -------- region A: h_s == h_{t-1}, x_s == x_t --------

        // prefetch x_{t+1} (threads 384..399), overlaps with the matvec below
        if (tid >= 384 && tid < 384 + I_ && (t + 1) < T_)
            xnext = x[(b * T_ + (t + 1)) * I_ + (tid - 384)];

        // gate pre-activation: bias + W_hh[g,:]·h + W_ih[g,:]·x_t
        float4 a4 = make_float4(0.f, 0.f, 0.f, 0.f);
        const float4* h4 = (const float4*)h_s;
        #pragma unroll
        for (int k = 0; k < H_ / 4; ++k) {
            float4 hv = h4[k];     // LDS broadcast read (all lanes same addr)
            a4.x = fmaf(hv.x, whh[k].x, a4.x);
            a4.y = fmaf(hv.y, whh[k].y, a4.y);
            a4.z = fmaf(hv.z, whh[k].z, a4.z);
            a4.w = fmaf(hv.w, whh[k].w, a4.w);
        }
        float a = bias + (a4.x + a4.y) + (a4.z + a4.w);
        {
            const float4* x4 = (const float4*)x_s;
            #pragma unroll
            for (int k = 0; k < I_ / 4; ++k) {
                float4 xv = x4[k];
                a = fmaf(xv.x, wih[4 * k + 0], a);
                a = fmaf(xv.y, wih[4 * k + 1], a);
                a = fmaf(xv.z, wih[4 * k + 2], a);
                a = fmaf(xv.w, wih[4 * k + 3], a);
            }
        }
        // activation: rows [0,256) = i,f sigmoid; [256,384) = g tanh; [384,512) = o sigmoid
        g_s[tid] = (tid < 256 || tid >= 384) ? sigmoid_f(a) : tanh_f(a);

        // fused FC + segment-sum for timestep t-1 (h_s still holds h_{t-1})
        if (t > 0 && id_prev >= 0) {
            if (tid < O_ * H_) {
                const int j = tid & 127, o = tid >> 7;
                float p = h_s[j] * wfc;
                #pragma unroll
                for (int off = 32; off >= 1; off >>= 1) p += __shfl_down(p, off);
                if ((tid & 63) == 0)
                    atomicAdd(&sums[(b * P_ + id_prev) * O_ + o], p);
            }
            if (tid == 0) atomicAdd(&counts[b * P_ + id_prev], 1.f);
        }

        // photo id of timestep t (x_s[2] holds it as an exact-integer float)
        {
            const int idc = (int)x_s[2];
            id_prev = (idc >= 0 && idc < P_) ? idc : -1;
        }

        __syncthreads();   // gates visible

        // -------- region B: state update --------
        if (tid < H_) {
            const float gi = g_s[tid];
            const float gf = g_s[128 + tid];
            const float gg = g_s[256 + tid];
            const float go = g_s[384 + tid];
            c = fmaf(gf, c, gi * gg);
            h_s[tid] = go * tanh_f(c);
        }
        if (tid >= 384 && tid < 384 + I_ && (t + 1) < T_)
            x_s[tid - 384] = xnext;
        __syncthreads();   // h_t, x_{t+1} visible
    }

    // tail: fused FC + segment-sum for t = T-1
    if (id_prev >= 0) {
        if (tid < O_ * H_) {
            const int j = tid & 127, o = tid >> 7;
            float p = h_s[j] * wfc;
            #pragma unroll
            for (int off = 32; off >= 1; off >>= 1) p += __shfl_down(p, off);
            if ((tid & 63) == 0)
                atomicAdd(&sums[(b * P_ + id_prev) * O_ + o], p);
        }
        if (tid == 0) atomicAdd(&counts[b * P_ + id_prev], 1.f);
    }
}

// out[b,p,o] = (sums[b,p,o] + cnt*b_fc[o]) / max(cnt,1)
__global__ void finalize_kernel(const float* __restrict__ sums,
                                const float* __restrict__ counts,
                                const float* __restrict__ b_fc,
                                float* __restrict__ out)
{
    const int idx = blockIdx.x * blockDim.x + threadIdx.x;
    if (idx >= B_ * P_ * O_) return;
    const int o  = idx % O_;
    const int bp = idx / O_;
    const float cnt = counts[bp];
    const float denom = (cnt > 0.f) ? cnt : 1.f;
    out[idx] = (sums[idx] + cnt * b_fc[o]) / denom;
}

extern "C" void kernel_launch(void* const* d_in, const int* in_sizes, int n_in,
                              void* d_out, int out_size, void* d_ws, size_t ws_size,
                              hipStream_t stream) {
    const float* x    = (const float*)d_in[0];
    const float* W_ih = (const float*)d_in[1];
    const float* W_hh = (const float*)d_in[2];
    const float* b_ih = (const float*)d_in[3];
    const float* b_hh = (const float*)d_in[4];
    const float* W_fc = (const float*)d_in[5];
    const float* b_fc = (const float*)d_in[6];
    // d_in[7] = num_photos (==P_, fixed by the problem)

    float* out    = (float*)d_out;
    float* sums   = (float*)d_ws;                 // B*P*3 floats
    float* counts = sums + (size_t)B_ * P_ * O_;  // B*P floats

    const size_t ws_bytes = ((size_t)B_ * P_ * O_ + (size_t)B_ * P_) * sizeof(float);
    hipMemsetAsync(d_ws, 0, ws_bytes, stream);

    lstm_fused<<<B_, 512, 0, stream>>>(x, W_ih, W_hh, b_ih, b_hh, W_fc, sums, counts);

    const int n = B_ * P_ * O_;
    finalize_kernel<<<(n + 255) / 256, 256, 0, stream>>>(sums, counts, b_fc, out);
}